// Round 9
// baseline (481.296 us; speedup 1.0000x reference)
//
#include <hip/hip_runtime.h>
#include <math.h>

// Plenoxels renderer, round 9 = round 7 + Morton-ordered voxel records.
//  - 32B records: 27 SH fp8(e4m3) + sigma fp16 + pad; vox = 64MiB, Morton
//    (z-order) indexed: an aligned 2x2x2 cell = 8 consecutive records =
//    4 consecutive cachelines (vs 4 scattered row-groups in linear layout).
//  - render: 4 samples/lane, 256-sample chunks, 2 chunks/ray, 8192 waves,
//    whole-wave early exit past box exit, folded sigmoid state.

typedef float f2v __attribute__((ext_vector_type(2)));

namespace {
constexpr float kRadius   = 1.3f;
constexpr int   kRes      = 128;
constexpr float kStep     = 2.0f * 1.3f / 128.0f / 2.0f;   // 0.01015625
constexpr int   kNI       = 443;                           // N_INTRS - 1
constexpr int   kNRays    = 4096;
constexpr int   kChStride = kRes * kRes * kRes;            // 2097152 voxels
constexpr int   kCh       = 28;
constexpr int   kRecBytes = 32;                            // 27 fp8 + f16 sigma + pad
constexpr size_t kVoxBytes = (size_t)kChStride * kRecBytes; // 64 MiB
constexpr int   kChunks   = 2;                             // 256-sample chunks
constexpr int   kChunks7  = 7;                             // fallback: 64-sample
}

// Morton helpers: spread 7 bits into every 3rd position / inverse.
__device__ __forceinline__ unsigned part1by2(unsigned v)
{
    v &= 0x7Fu;
    v = (v | (v << 16)) & 0x030000FFu;
    v = (v | (v <<  8)) & 0x0300F00Fu;
    v = (v | (v <<  4)) & 0x030C30C3u;
    v = (v | (v <<  2)) & 0x09249249u;
    return v;
}
__device__ __forceinline__ unsigned compact1by2(unsigned v)
{
    v &= 0x09249249u;
    v = (v ^ (v >>  2)) & 0x030C30C3u;
    v = (v ^ (v >>  4)) & 0x0300F00Fu;
    v = (v ^ (v >>  8)) & 0x030000FFu;
    v = (v ^ (v >> 16)) & 0x000003FFu;
    return v;
}

// ---------------------------------------------------------------------------
// Convert grid[c][(z,y,x) linear] -> vox[morton(x,y,z)] 32B record.
// Output-driven: thread's record index is its Morton code -> writes fully
// coalesced; reads are 16B-granular within 4x4x4 blocks (L2 absorbs).
// ---------------------------------------------------------------------------
__global__ __launch_bounds__(256)
void convert_grid(const float* __restrict__ grid, unsigned char* __restrict__ vox)
{
    const unsigned m = blockIdx.x * 256 + threadIdx.x;     // Morton code
    const unsigned x = compact1by2(m);
    const unsigned y = compact1by2(m >> 1);
    const unsigned z = compact1by2(m >> 2);
    const unsigned lin = (z << 14) + (y << 7) + x;

    float c[kCh];
    #pragma unroll
    for (int ch = 0; ch < kCh; ++ch)
        c[ch] = __builtin_nontemporal_load(grid + (size_t)ch * kChStride + lin);

    unsigned w[8];
    #pragma unroll
    for (int i = 0; i < 6; ++i) {
        int lo = __builtin_amdgcn_cvt_pk_fp8_f32(c[4*i],   c[4*i+1], 0,  false);
        w[i]   = (unsigned)__builtin_amdgcn_cvt_pk_fp8_f32(c[4*i+2], c[4*i+3], lo, true);
    }
    {   // word 6: ch24,25,26 + pad byte
        int lo = __builtin_amdgcn_cvt_pk_fp8_f32(c[24], c[25], 0,  false);
        w[6]   = (unsigned)__builtin_amdgcn_cvt_pk_fp8_f32(c[26], 0.0f, lo, true);
    }
    {   // word 7: fp16 sigma in low half
        union { unsigned short u; _Float16 h; } cv;
        cv.h = (_Float16)c[27];
        w[7] = (unsigned)cv.u;
    }

    uint4* dst = (uint4*)(vox + (size_t)m * kRecBytes);
    dst[0] = make_uint4(w[0], w[1], w[2], w[3]);
    dst[1] = make_uint4(w[4], w[5], w[6], w[7]);
}

// ---------------------------------------------------------------------------
// Per-sample eval with folded shading.  Returns:
//   a  = 1 - alpha + 1e-10 (or exactly 1.0 for k >= kNI)
//   cR/cG/cB = alpha * sigmoid(rp)  (0 when out of box)
// ---------------------------------------------------------------------------
struct SampleC { float a, cR, cG, cB; };

__device__ __forceinline__ SampleC eval_sample(
    int k, float start, float ox, float oy, float oz,
    float dx, float dy, float dz, float dist,
    const float* __restrict__ shm, const unsigned char* __restrict__ vox)
{
    SampleC s;
    s.a = 1.f; s.cR = s.cG = s.cB = 0.f;
    if (k >= kNI) return s;

    const float t  = start + (float)k * kStep;
    const float px = ox + t*dx;
    const float py = oy + t*dy;
    const float pz = oz + t*dz;
    const bool inb = (px > -kRadius) && (px < kRadius) &&
                     (py > -kRadius) && (py < kRadius) &&
                     (pz > -kRadius) && (pz < kRadius);

    float alpha = 0.0f;
    if (inb) {
        const float cx = fminf(fmaxf((px*(1.0f/kRadius) + 1.0f)*0.5f*127.0f, 0.0f), 127.0f);
        const float cy = fminf(fmaxf((py*(1.0f/kRadius) + 1.0f)*0.5f*127.0f, 0.0f), 127.0f);
        const float cz = fminf(fmaxf((pz*(1.0f/kRadius) + 1.0f)*0.5f*127.0f, 0.0f), 127.0f);
        const float fx0 = floorf(cx), fy0 = floorf(cy), fz0 = floorf(cz);
        const float fx = cx - fx0, fy = cy - fy0, fz = cz - fz0;
        const int ix0 = (int)fx0, iy0 = (int)fy0, iz0 = (int)fz0;
        const int ix1 = min(ix0 + 1, 127);
        const int iy1 = min(iy0 + 1, 127);
        const int iz1 = min(iz0 + 1, 127);

        const float gx0 = 1.0f - fx, gy0 = 1.0f - fy, gz0 = 1.0f - fz;

        // Morton corner indices
        const unsigned X0 = part1by2((unsigned)ix0);
        const unsigned X1 = part1by2((unsigned)ix1);
        const unsigned Y0 = part1by2((unsigned)iy0) << 1;
        const unsigned Y1 = part1by2((unsigned)iy1) << 1;
        const unsigned Z0 = part1by2((unsigned)iz0) << 2;
        const unsigned Z1 = part1by2((unsigned)iz1) << 2;

        const unsigned offs[8] = {
            Z0 | Y0 | X0,  Z0 | Y0 | X1,  Z0 | Y1 | X0,  Z0 | Y1 | X1,
            Z1 | Y0 | X0,  Z1 | Y0 | X1,  Z1 | Y1 | X0,  Z1 | Y1 | X1 };
        const float cw[8] = {
            gz0*gy0*gx0, gz0*gy0*fx, gz0*fy*gx0, gz0*fy*fx,
            fz *gy0*gx0, fz *gy0*fx, fz *fy*gx0, fz *fy*fx };

        float rp0 = 0.f, rp1 = 0.f, rp2 = 0.f, sig = 0.f;
        #pragma unroll
        for (int cn = 0; cn < 8; ++cn) {
            const uint4* vp = (const uint4*)(vox + (size_t)offs[cn] * kRecBytes);
            const uint4 u0 = vp[0], u1 = vp[1];

            float f[28];
            const unsigned wd[7] = { u0.x, u0.y, u0.z, u0.w, u1.x, u1.y, u1.z };
            #pragma unroll
            for (int i = 0; i < 7; ++i) {
                const f2v lo = __builtin_amdgcn_cvt_pk_f32_fp8((int)wd[i], false);
                const f2v hi = __builtin_amdgcn_cvt_pk_f32_fp8((int)wd[i], true);
                f[4*i+0] = lo.x; f[4*i+1] = lo.y; f[4*i+2] = hi.x; f[4*i+3] = hi.y;
            }
            union { unsigned short u; _Float16 h; } cv;
            cv.u = (unsigned short)(u1.w & 0xffffu);
            const float sv = (float)cv.h;

            float r = 0.f, g = 0.f, b = 0.f;
            #pragma unroll
            for (int j = 0; j < 9; ++j) {
                r = fmaf(shm[j], f[j],      r);
                g = fmaf(shm[j], f[9 + j],  g);
                b = fmaf(shm[j], f[18 + j], b);
            }
            const float wc = cw[cn];
            rp0 = fmaf(wc, r, rp0);
            rp1 = fmaf(wc, g, rp1);
            rp2 = fmaf(wc, b, rp2);
            sig = fmaf(wc, sv, sig);
        }
        sig = fmaxf(sig, 0.0f);
        alpha = 1.0f - expf(-sig * dist);
        s.cR = alpha * (1.0f / (1.0f + expf(-rp0)));
        s.cG = alpha * (1.0f / (1.0f + expf(-rp1)));
        s.cB = alpha * (1.0f / (1.0f + expf(-rp2)));
    }
    s.a = 1.0f - alpha + 1e-10f;
    return s;
}

__device__ __forceinline__ float wave_scan_prod(float a, int lane, float& total)
{
    float prod = a;
    #pragma unroll
    for (int off = 1; off < 64; off <<= 1) {
        const float y = __shfl_up(prod, off, 64);
        if (lane >= off) prod *= y;
    }
    float excl = __shfl_up(prod, 1, 64);
    if (lane == 0) excl = 1.0f;
    total = __shfl(prod, 63, 64);
    return excl;
}

// ---------------------------------------------------------------------------
// Render one 256-sample chunk of one ray per wave; lane handles samples
// base+lane+{0,64,128,192}.  Emits S_R,S_G,S_B,S_L (unit carry) + P.
// ---------------------------------------------------------------------------
__global__ __launch_bounds__(256, 3)
void render_chunks(const float* __restrict__ rays_o,
                   const float* __restrict__ rays_d,
                   const unsigned char* __restrict__ vox,
                   float* __restrict__ partials)           // (4096,2,5)
{
    const int lane  = threadIdx.x & 63;
    const int W     = blockIdx.x * 4 + (threadIdx.x >> 6); // 8192 waves
    const int ray   = W >> 1;
    const int chunk = W & 1;

    const float ox = rays_o[3*ray+0], oy = rays_o[3*ray+1], oz = rays_o[3*ray+2];
    const float dx = rays_d[3*ray+0], dy = rays_d[3*ray+1], dz = rays_d[3*ray+2];

    const float ppx = ( kRadius - ox)/dx, pnx = (-kRadius - ox)/dx;
    const float ppy = ( kRadius - oy)/dy, pny = (-kRadius - oy)/dy;
    const float ppz = ( kRadius - oz)/dz, pnz = (-kRadius - oz)/dz;
    const float start  = fmaxf(fminf(ppx, pnx), fmaxf(fminf(ppy, pny), fminf(ppz, pnz)));
    const float t_exit = fminf(fmaxf(ppx, pnx), fminf(fmaxf(ppy, pny), fmaxf(ppz, pnz)));

    const int base = chunk * 256;

    // whole-wave early exit: chunk starts beyond box exit (one-step margin)
    if (start + (float)base * kStep > t_exit + kStep) {
        if (lane == 0) {
            float* p = partials + (size_t)(ray * kChunks + chunk) * 5;
            p[0] = 0.f; p[1] = 0.f; p[2] = 0.f; p[3] = 0.f; p[4] = 1.f;
        }
        return;
    }

    const float dnorm = sqrtf(dx*dx + dy*dy + dz*dz);
    const float dist  = kStep * dnorm;

    float shm[9];
    shm[0] =  0.28209479177387814f;
    shm[1] = -0.4886025119029199f * dy;
    shm[2] =  0.4886025119029199f * dz;
    shm[3] = -0.4886025119029199f * dx;
    shm[4] =  1.0925484305920792f * dx * dy;
    shm[5] = -1.0925484305920792f * dy * dz;
    shm[6] =  0.31539156525252005f * (2.0f*dz*dz - dx*dx - dy*dy);
    shm[7] = -1.0925484305920792f * dx * dz;
    shm[8] =  0.5462742152960396f * (dx*dx - dy*dy);

    const SampleC A = eval_sample(base       + lane, start, ox, oy, oz, dx, dy, dz, dist, shm, vox);
    const SampleC B = eval_sample(base +  64 + lane, start, ox, oy, oz, dx, dy, dz, dist, shm, vox);
    const SampleC C = eval_sample(base + 128 + lane, start, ox, oy, oz, dx, dy, dz, dist, shm, vox);
    const SampleC D = eval_sample(base + 192 + lane, start, ox, oy, oz, dx, dy, dz, dist, shm, vox);

    float P0, P1, P2, P3;
    const float eA = wave_scan_prod(A.a, lane, P0);
    const float eB = wave_scan_prod(B.a, lane, P1);
    const float eC = wave_scan_prod(C.a, lane, P2);
    const float eD = wave_scan_prod(D.a, lane, P3);

    const float pA = eA;
    const float pB = P0 * eB;
    const float pC = P0 * P1 * eC;
    const float pD = P0 * P1 * P2 * eD;

    const float one = 1.0f + 1e-10f;
    float rL = pA * (one - A.a) + pB * (one - B.a)
             + pC * (one - C.a) + pD * (one - D.a);

    float rR = pA * A.cR;  rR = fmaf(pB, B.cR, rR);
    rR = fmaf(pC, C.cR, rR);  rR = fmaf(pD, D.cR, rR);
    float rG = pA * A.cG;  rG = fmaf(pB, B.cG, rG);
    rG = fmaf(pC, C.cG, rG);  rG = fmaf(pD, D.cG, rG);
    float rB = pA * A.cB;  rB = fmaf(pB, B.cB, rB);
    rB = fmaf(pC, C.cB, rB);  rB = fmaf(pD, D.cB, rB);

    const float P = P0 * P1 * P2 * P3;

    #pragma unroll
    for (int off = 32; off > 0; off >>= 1) {
        rR += __shfl_down(rR, off, 64);
        rG += __shfl_down(rG, off, 64);
        rB += __shfl_down(rB, off, 64);
        rL += __shfl_down(rL, off, 64);
    }

    if (lane == 0) {
        float* p = partials + (size_t)(ray * kChunks + chunk) * 5;
        p[0] = rR; p[1] = rG; p[2] = rB; p[3] = rL; p[4] = P;
    }
}

// ---------------------------------------------------------------------------
// Stitch chunk partials: acc += carry * S_c ; carry *= P_c.
// ---------------------------------------------------------------------------
__global__ __launch_bounds__(256)
void combine_chunks(const float* __restrict__ partials, float* __restrict__ out)
{
    const int r = blockIdx.x * 256 + threadIdx.x;          // 16 blocks
    const float* p = partials + (size_t)r * (kChunks * 5);

    float carry = 1.0f, aR = 0.f, aG = 0.f, aB = 0.f, aL = 0.f;
    #pragma unroll
    for (int c = 0; c < kChunks; ++c) {
        aR = fmaf(carry, p[c*5 + 0], aR);
        aG = fmaf(carry, p[c*5 + 1], aG);
        aB = fmaf(carry, p[c*5 + 2], aB);
        aL = fmaf(carry, p[c*5 + 3], aL);
        carry *= p[c*5 + 4];
    }
    const float bg = 1.0f - aL;
    out[3*r + 0] = aR + bg;
    out[3*r + 1] = aG + bg;
    out[3*r + 2] = aB + bg;
}

// ---------------------------------------------------------------------------
// Fallback: direct channel-major render (round-1 style) if ws too small.
// ---------------------------------------------------------------------------
#define TRI8(p) (w000*(p)[o000] + w001*(p)[o001] + w010*(p)[o010] + w011*(p)[o011] \
               + w100*(p)[o100] + w101*(p)[o101] + w110*(p)[o110] + w111*(p)[o111])

__global__ __launch_bounds__(256)
void plenoxel_render_direct(const float* __restrict__ rays_o,
                            const float* __restrict__ rays_d,
                            const float* __restrict__ grid,
                            float* __restrict__ out)
{
    const int lane = threadIdx.x & 63;
    const int ray  = blockIdx.x * 4 + (threadIdx.x >> 6);

    const float ox = rays_o[3*ray+0], oy = rays_o[3*ray+1], oz = rays_o[3*ray+2];
    const float dx = rays_d[3*ray+0], dy = rays_d[3*ray+1], dz = rays_d[3*ray+2];

    const float sx = fminf(( kRadius - ox)/dx, (-kRadius - ox)/dx);
    const float sy = fminf(( kRadius - oy)/dy, (-kRadius - oy)/dy);
    const float sz = fminf(( kRadius - oz)/dz, (-kRadius - oz)/dz);
    const float start = fmaxf(sx, fmaxf(sy, sz));
    const float dnorm = sqrtf(dx*dx + dy*dy + dz*dz);

    float shm[9];
    shm[0] =  0.28209479177387814f;
    shm[1] = -0.4886025119029199f * dy;
    shm[2] =  0.4886025119029199f * dz;
    shm[3] = -0.4886025119029199f * dx;
    shm[4] =  1.0925484305920792f * dx * dy;
    shm[5] = -1.0925484305920792f * dy * dz;
    shm[6] =  0.31539156525252005f * (2.0f*dz*dz - dx*dx - dy*dy);
    shm[7] = -1.0925484305920792f * dx * dz;
    shm[8] =  0.5462742152960396f * (dx*dx - dy*dy);

    float carry = 1.0f;
    float accR = 0.f, accG = 0.f, accB = 0.f, accL = 0.f;

    for (int chunk = 0; chunk < kChunks7; ++chunk) {
        const int k = chunk * 64 + lane;
        float alpha = 0.0f, a = 1.0f;
        float rp0 = 0.f, rp1 = 0.f, rp2 = 0.f;
        bool inb = false;

        if (k < kNI) {
            const float t = start + (float)k * kStep;
            const float dist = kStep * dnorm;
            const float px = ox + t*dx, py = oy + t*dy, pz = oz + t*dz;
            inb = (px > -kRadius) && (px < kRadius) &&
                  (py > -kRadius) && (py < kRadius) &&
                  (pz > -kRadius) && (pz < kRadius);
            float sigma = 0.0f;
            if (inb) {
                const float cx = fminf(fmaxf((px*(1.0f/kRadius) + 1.0f)*0.5f*127.0f, 0.0f), 127.0f);
                const float cy = fminf(fmaxf((py*(1.0f/kRadius) + 1.0f)*0.5f*127.0f, 0.0f), 127.0f);
                const float cz = fminf(fmaxf((pz*(1.0f/kRadius) + 1.0f)*0.5f*127.0f, 0.0f), 127.0f);
                const float fx0 = floorf(cx), fy0 = floorf(cy), fz0 = floorf(cz);
                const float fx = cx - fx0, fy = cy - fy0, fz = cz - fz0;
                const int ix0 = (int)fx0, iy0 = (int)fy0, iz0 = (int)fz0;
                const int ix1 = min(ix0 + 1, 127);
                const int iy1 = min(iy0 + 1, 127);
                const int iz1 = min(iz0 + 1, 127);
                const float gx0 = 1.0f - fx, gy0 = 1.0f - fy, gz0 = 1.0f - fz;
                const float w000 = gz0*gy0*gx0, w001 = gz0*gy0*fx;
                const float w010 = gz0*fy *gx0, w011 = gz0*fy *fx;
                const float w100 = fz *gy0*gx0, w101 = fz *gy0*fx;
                const float w110 = fz *fy *gx0, w111 = fz *fy *fx;
                const int o000 = iz0*(kRes*kRes) + iy0*kRes + ix0;
                const int o001 = iz0*(kRes*kRes) + iy0*kRes + ix1;
                const int o010 = iz0*(kRes*kRes) + iy1*kRes + ix0;
                const int o011 = iz0*(kRes*kRes) + iy1*kRes + ix1;
                const int o100 = iz1*(kRes*kRes) + iy0*kRes + ix0;
                const int o101 = iz1*(kRes*kRes) + iy0*kRes + ix1;
                const int o110 = iz1*(kRes*kRes) + iy1*kRes + ix0;
                const int o111 = iz1*(kRes*kRes) + iy1*kRes + ix1;
                #pragma unroll
                for (int kk = 0; kk < 9; ++kk) {
                    rp0 = fmaf(shm[kk], TRI8(grid + (kk     ) * kChStride), rp0);
                    rp1 = fmaf(shm[kk], TRI8(grid + (kk +  9) * kChStride), rp1);
                    rp2 = fmaf(shm[kk], TRI8(grid + (kk + 18) * kChStride), rp2);
                }
                sigma = fmaxf(TRI8(grid + 27 * kChStride), 0.0f);
            }
            alpha = 1.0f - expf(-sigma * dist);
            a     = 1.0f - alpha + 1e-10f;
        }

        float prod = a;
        #pragma unroll
        for (int off = 1; off < 64; off <<= 1) {
            const float y = __shfl_up(prod, off, 64);
            if (lane >= off) prod *= y;
        }
        float excl = __shfl_up(prod, 1, 64);
        if (lane == 0) excl = 1.0f;
        const float trans = carry * excl;
        const float w = alpha * trans;
        if (inb) {
            accR = fmaf(w, 1.0f / (1.0f + expf(-rp0)), accR);
            accG = fmaf(w, 1.0f / (1.0f + expf(-rp1)), accG);
            accB = fmaf(w, 1.0f / (1.0f + expf(-rp2)), accB);
        }
        accL += w;
        carry *= __shfl(prod, 63, 64);
    }

    #pragma unroll
    for (int off = 32; off > 0; off >>= 1) {
        accR += __shfl_down(accR, off, 64);
        accG += __shfl_down(accG, off, 64);
        accB += __shfl_down(accB, off, 64);
        accL += __shfl_down(accL, off, 64);
    }

    if (lane == 0) {
        const float bg = 1.0f - accL;
        out[3*ray + 0] = accR + bg;
        out[3*ray + 1] = accG + bg;
        out[3*ray + 2] = accB + bg;
    }
}

extern "C" void kernel_launch(void* const* d_in, const int* in_sizes, int n_in,
                              void* d_out, int out_size, void* d_ws, size_t ws_size,
                              hipStream_t stream) {
    const float* rays_o = (const float*)d_in[0];
    const float* rays_d = (const float*)d_in[1];
    const float* data   = (const float*)d_in[2];   // (1,28,128,128,128)
    float* out = (float*)d_out;

    const size_t partBytes = (size_t)kNRays * kChunks * 5 * sizeof(float);
    const size_t need = kVoxBytes + partBytes;     // ~64.2 MB

    if (ws_size >= need) {
        unsigned char* vox = (unsigned char*)d_ws;
        float* partials = (float*)((char*)d_ws + kVoxBytes);

        hipLaunchKernelGGL(convert_grid,
                           dim3(kChStride / 256), dim3(256), 0, stream,
                           data, vox);
        hipLaunchKernelGGL(render_chunks,
                           dim3(kNRays * kChunks / 4), dim3(256), 0, stream,
                           rays_o, rays_d, vox, partials);
        hipLaunchKernelGGL(combine_chunks,
                           dim3(kNRays / 256), dim3(256), 0, stream,
                           partials, out);
    } else {
        hipLaunchKernelGGL(plenoxel_render_direct,
                           dim3(kNRays / 4), dim3(256), 0, stream,
                           rays_o, rays_d, data, out);
    }
}

// Round 10
// 404.673 us; speedup vs baseline: 1.1893x; 1.1893x over previous
//
#include <hip/hip_runtime.h>
#include <math.h>

// Plenoxels renderer, round 10 = round-9 Morton render + tiled LDS convert.
//  - 32B records: 27 SH fp8(e4m3) + sigma fp16 + pad; vox = 64MiB, Morton
//    indexed (render proved ~2x faster vs linear in round 9).
//  - convert: workgroup = 16x8x8 tile -> one contiguous 1024-record Morton
//    range.  Phase 1: linear-coalesced reads (full 64B lines), convert,
//    scatter 32B records into LDS Morton slots.  Phase 2: stream 32KB LDS
//    to global contiguously.  Both sides fully coalesced.
//  - render: 4 samples/lane, 256-sample chunks, 2 chunks/ray, 8192 waves,
//    whole-wave early exit, folded sigmoid state.

typedef float f2v __attribute__((ext_vector_type(2)));

namespace {
constexpr float kRadius   = 1.3f;
constexpr int   kRes      = 128;
constexpr float kStep     = 2.0f * 1.3f / 128.0f / 2.0f;   // 0.01015625
constexpr int   kNI       = 443;                           // N_INTRS - 1
constexpr int   kNRays    = 4096;
constexpr int   kChStride = kRes * kRes * kRes;            // 2097152 voxels
constexpr int   kCh       = 28;
constexpr int   kRecBytes = 32;                            // 27 fp8 + f16 sigma + pad
constexpr size_t kVoxBytes = (size_t)kChStride * kRecBytes; // 64 MiB
constexpr int   kChunks   = 2;                             // 256-sample chunks
constexpr int   kChunks7  = 7;                             // fallback: 64-sample
}

// Morton helpers.
__device__ __forceinline__ unsigned part1by2(unsigned v)   // 7-bit spread
{
    v &= 0x7Fu;
    v = (v | (v << 16)) & 0x030000FFu;
    v = (v | (v <<  8)) & 0x0300F00Fu;
    v = (v | (v <<  4)) & 0x030C30C3u;
    v = (v | (v <<  2)) & 0x09249249u;
    return v;
}
__device__ __forceinline__ unsigned m3(unsigned v)         // 3-bit spread
{
    return (v & 1u) | ((v & 2u) << 2) | ((v & 4u) << 4);
}

// ---------------------------------------------------------------------------
// Convert: one block = 16x8x8 tile = contiguous Morton range [base, base+1024).
// ---------------------------------------------------------------------------
__global__ __launch_bounds__(256)
void convert_grid(const float* __restrict__ grid, unsigned char* __restrict__ vox)
{
    __shared__ uint4 lds[2048];                            // 1024 records x 32B

    const int t  = threadIdx.x;
    const unsigned tile = blockIdx.x;                      // 2048 tiles
    const unsigned X = (tile & 7u) << 4;                   // 8 tiles in x
    const unsigned Y = ((tile >> 3) & 15u) << 3;           // 16 in y
    const unsigned Z = (tile >> 7) << 3;                   // 16 in z

    // phase 1: read linear rows (full 64B lines), convert, LDS-scatter
    #pragma unroll
    for (int v = 0; v < 4; ++v) {
        const int l = v * 256 + t;                         // local linear idx
        const unsigned lx = l & 15u;
        const unsigned ly = ((unsigned)l >> 4) & 7u;
        const unsigned lz = (unsigned)l >> 7;
        const unsigned lin = (Z + lz) * 16384u + (Y + ly) * 128u + (X + lx);

        float c[kCh];
        #pragma unroll
        for (int ch = 0; ch < kCh; ++ch)
            c[ch] = __builtin_nontemporal_load(grid + (size_t)ch * kChStride + lin);

        unsigned w[8];
        #pragma unroll
        for (int i = 0; i < 6; ++i) {
            int lo = __builtin_amdgcn_cvt_pk_fp8_f32(c[4*i],   c[4*i+1], 0,  false);
            w[i]   = (unsigned)__builtin_amdgcn_cvt_pk_fp8_f32(c[4*i+2], c[4*i+3], lo, true);
        }
        {
            int lo = __builtin_amdgcn_cvt_pk_fp8_f32(c[24], c[25], 0,  false);
            w[6]   = (unsigned)__builtin_amdgcn_cvt_pk_fp8_f32(c[26], 0.0f, lo, true);
        }
        {
            union { unsigned short u; _Float16 h; } cv;
            cv.h = (_Float16)c[27];
            w[7] = (unsigned)cv.u;
        }

        const unsigned s = (m3(lx & 7u) | (m3(ly) << 1) | (m3(lz) << 2))
                         + ((lx >> 3) << 9);               // local Morton slot
        lds[2*s + 0] = make_uint4(w[0], w[1], w[2], w[3]);
        lds[2*s + 1] = make_uint4(w[4], w[5], w[6], w[7]);
    }
    __syncthreads();

    // phase 2: stream 32KB LDS -> contiguous global Morton range
    const unsigned base = part1by2(X) | (part1by2(Y) << 1) | (part1by2(Z) << 2);
    uint4* dst = (uint4*)(vox + (size_t)base * kRecBytes);
    #pragma unroll
    for (int i = 0; i < 8; ++i) {
        const int j = i * 256 + t;
        dst[j] = lds[j];
    }
}

// ---------------------------------------------------------------------------
// Per-sample eval with folded shading (Morton-indexed records).
// ---------------------------------------------------------------------------
struct SampleC { float a, cR, cG, cB; };

__device__ __forceinline__ SampleC eval_sample(
    int k, float start, float ox, float oy, float oz,
    float dx, float dy, float dz, float dist,
    const float* __restrict__ shm, const unsigned char* __restrict__ vox)
{
    SampleC s;
    s.a = 1.f; s.cR = s.cG = s.cB = 0.f;
    if (k >= kNI) return s;

    const float t  = start + (float)k * kStep;
    const float px = ox + t*dx;
    const float py = oy + t*dy;
    const float pz = oz + t*dz;
    const bool inb = (px > -kRadius) && (px < kRadius) &&
                     (py > -kRadius) && (py < kRadius) &&
                     (pz > -kRadius) && (pz < kRadius);

    float alpha = 0.0f;
    if (inb) {
        const float cx = fminf(fmaxf((px*(1.0f/kRadius) + 1.0f)*0.5f*127.0f, 0.0f), 127.0f);
        const float cy = fminf(fmaxf((py*(1.0f/kRadius) + 1.0f)*0.5f*127.0f, 0.0f), 127.0f);
        const float cz = fminf(fmaxf((pz*(1.0f/kRadius) + 1.0f)*0.5f*127.0f, 0.0f), 127.0f);
        const float fx0 = floorf(cx), fy0 = floorf(cy), fz0 = floorf(cz);
        const float fx = cx - fx0, fy = cy - fy0, fz = cz - fz0;
        const int ix0 = (int)fx0, iy0 = (int)fy0, iz0 = (int)fz0;
        const int ix1 = min(ix0 + 1, 127);
        const int iy1 = min(iy0 + 1, 127);
        const int iz1 = min(iz0 + 1, 127);

        const float gx0 = 1.0f - fx, gy0 = 1.0f - fy, gz0 = 1.0f - fz;

        const unsigned X0 = part1by2((unsigned)ix0);
        const unsigned X1 = part1by2((unsigned)ix1);
        const unsigned Y0 = part1by2((unsigned)iy0) << 1;
        const unsigned Y1 = part1by2((unsigned)iy1) << 1;
        const unsigned Z0 = part1by2((unsigned)iz0) << 2;
        const unsigned Z1 = part1by2((unsigned)iz1) << 2;

        const unsigned offs[8] = {
            Z0 | Y0 | X0,  Z0 | Y0 | X1,  Z0 | Y1 | X0,  Z0 | Y1 | X1,
            Z1 | Y0 | X0,  Z1 | Y0 | X1,  Z1 | Y1 | X0,  Z1 | Y1 | X1 };
        const float cw[8] = {
            gz0*gy0*gx0, gz0*gy0*fx, gz0*fy*gx0, gz0*fy*fx,
            fz *gy0*gx0, fz *gy0*fx, fz *fy*gx0, fz *fy*fx };

        float rp0 = 0.f, rp1 = 0.f, rp2 = 0.f, sig = 0.f;
        #pragma unroll
        for (int cn = 0; cn < 8; ++cn) {
            const uint4* vp = (const uint4*)(vox + (size_t)offs[cn] * kRecBytes);
            const uint4 u0 = vp[0], u1 = vp[1];

            float f[28];
            const unsigned wd[7] = { u0.x, u0.y, u0.z, u0.w, u1.x, u1.y, u1.z };
            #pragma unroll
            for (int i = 0; i < 7; ++i) {
                const f2v lo = __builtin_amdgcn_cvt_pk_f32_fp8((int)wd[i], false);
                const f2v hi = __builtin_amdgcn_cvt_pk_f32_fp8((int)wd[i], true);
                f[4*i+0] = lo.x; f[4*i+1] = lo.y; f[4*i+2] = hi.x; f[4*i+3] = hi.y;
            }
            union { unsigned short u; _Float16 h; } cv;
            cv.u = (unsigned short)(u1.w & 0xffffu);
            const float sv = (float)cv.h;

            float r = 0.f, g = 0.f, b = 0.f;
            #pragma unroll
            for (int j = 0; j < 9; ++j) {
                r = fmaf(shm[j], f[j],      r);
                g = fmaf(shm[j], f[9 + j],  g);
                b = fmaf(shm[j], f[18 + j], b);
            }
            const float wc = cw[cn];
            rp0 = fmaf(wc, r, rp0);
            rp1 = fmaf(wc, g, rp1);
            rp2 = fmaf(wc, b, rp2);
            sig = fmaf(wc, sv, sig);
        }
        sig = fmaxf(sig, 0.0f);
        alpha = 1.0f - expf(-sig * dist);
        s.cR = alpha * (1.0f / (1.0f + expf(-rp0)));
        s.cG = alpha * (1.0f / (1.0f + expf(-rp1)));
        s.cB = alpha * (1.0f / (1.0f + expf(-rp2)));
    }
    s.a = 1.0f - alpha + 1e-10f;
    return s;
}

__device__ __forceinline__ float wave_scan_prod(float a, int lane, float& total)
{
    float prod = a;
    #pragma unroll
    for (int off = 1; off < 64; off <<= 1) {
        const float y = __shfl_up(prod, off, 64);
        if (lane >= off) prod *= y;
    }
    float excl = __shfl_up(prod, 1, 64);
    if (lane == 0) excl = 1.0f;
    total = __shfl(prod, 63, 64);
    return excl;
}

// ---------------------------------------------------------------------------
// Render one 256-sample chunk of one ray per wave.
// ---------------------------------------------------------------------------
__global__ __launch_bounds__(256, 3)
void render_chunks(const float* __restrict__ rays_o,
                   const float* __restrict__ rays_d,
                   const unsigned char* __restrict__ vox,
                   float* __restrict__ partials)           // (4096,2,5)
{
    const int lane  = threadIdx.x & 63;
    const int W     = blockIdx.x * 4 + (threadIdx.x >> 6); // 8192 waves
    const int ray   = W >> 1;
    const int chunk = W & 1;

    const float ox = rays_o[3*ray+0], oy = rays_o[3*ray+1], oz = rays_o[3*ray+2];
    const float dx = rays_d[3*ray+0], dy = rays_d[3*ray+1], dz = rays_d[3*ray+2];

    const float ppx = ( kRadius - ox)/dx, pnx = (-kRadius - ox)/dx;
    const float ppy = ( kRadius - oy)/dy, pny = (-kRadius - oy)/dy;
    const float ppz = ( kRadius - oz)/dz, pnz = (-kRadius - oz)/dz;
    const float start  = fmaxf(fminf(ppx, pnx), fmaxf(fminf(ppy, pny), fminf(ppz, pnz)));
    const float t_exit = fminf(fmaxf(ppx, pnx), fminf(fmaxf(ppy, pny), fmaxf(ppz, pnz)));

    const int base = chunk * 256;

    if (start + (float)base * kStep > t_exit + kStep) {
        if (lane == 0) {
            float* p = partials + (size_t)(ray * kChunks + chunk) * 5;
            p[0] = 0.f; p[1] = 0.f; p[2] = 0.f; p[3] = 0.f; p[4] = 1.f;
        }
        return;
    }

    const float dnorm = sqrtf(dx*dx + dy*dy + dz*dz);
    const float dist  = kStep * dnorm;

    float shm[9];
    shm[0] =  0.28209479177387814f;
    shm[1] = -0.4886025119029199f * dy;
    shm[2] =  0.4886025119029199f * dz;
    shm[3] = -0.4886025119029199f * dx;
    shm[4] =  1.0925484305920792f * dx * dy;
    shm[5] = -1.0925484305920792f * dy * dz;
    shm[6] =  0.31539156525252005f * (2.0f*dz*dz - dx*dx - dy*dy);
    shm[7] = -1.0925484305920792f * dx * dz;
    shm[8] =  0.5462742152960396f * (dx*dx - dy*dy);

    const SampleC A = eval_sample(base       + lane, start, ox, oy, oz, dx, dy, dz, dist, shm, vox);
    const SampleC B = eval_sample(base +  64 + lane, start, ox, oy, oz, dx, dy, dz, dist, shm, vox);
    const SampleC C = eval_sample(base + 128 + lane, start, ox, oy, oz, dx, dy, dz, dist, shm, vox);
    const SampleC D = eval_sample(base + 192 + lane, start, ox, oy, oz, dx, dy, dz, dist, shm, vox);

    float P0, P1, P2, P3;
    const float eA = wave_scan_prod(A.a, lane, P0);
    const float eB = wave_scan_prod(B.a, lane, P1);
    const float eC = wave_scan_prod(C.a, lane, P2);
    const float eD = wave_scan_prod(D.a, lane, P3);

    const float pA = eA;
    const float pB = P0 * eB;
    const float pC = P0 * P1 * eC;
    const float pD = P0 * P1 * P2 * eD;

    const float one = 1.0f + 1e-10f;
    float rL = pA * (one - A.a) + pB * (one - B.a)
             + pC * (one - C.a) + pD * (one - D.a);

    float rR = pA * A.cR;  rR = fmaf(pB, B.cR, rR);
    rR = fmaf(pC, C.cR, rR);  rR = fmaf(pD, D.cR, rR);
    float rG = pA * A.cG;  rG = fmaf(pB, B.cG, rG);
    rG = fmaf(pC, C.cG, rG);  rG = fmaf(pD, D.cG, rG);
    float rB = pA * A.cB;  rB = fmaf(pB, B.cB, rB);
    rB = fmaf(pC, C.cB, rB);  rB = fmaf(pD, D.cB, rB);

    const float P = P0 * P1 * P2 * P3;

    #pragma unroll
    for (int off = 32; off > 0; off >>= 1) {
        rR += __shfl_down(rR, off, 64);
        rG += __shfl_down(rG, off, 64);
        rB += __shfl_down(rB, off, 64);
        rL += __shfl_down(rL, off, 64);
    }

    if (lane == 0) {
        float* p = partials + (size_t)(ray * kChunks + chunk) * 5;
        p[0] = rR; p[1] = rG; p[2] = rB; p[3] = rL; p[4] = P;
    }
}

// ---------------------------------------------------------------------------
// Stitch chunk partials.
// ---------------------------------------------------------------------------
__global__ __launch_bounds__(256)
void combine_chunks(const float* __restrict__ partials, float* __restrict__ out)
{
    const int r = blockIdx.x * 256 + threadIdx.x;          // 16 blocks
    const float* p = partials + (size_t)r * (kChunks * 5);

    float carry = 1.0f, aR = 0.f, aG = 0.f, aB = 0.f, aL = 0.f;
    #pragma unroll
    for (int c = 0; c < kChunks; ++c) {
        aR = fmaf(carry, p[c*5 + 0], aR);
        aG = fmaf(carry, p[c*5 + 1], aG);
        aB = fmaf(carry, p[c*5 + 2], aB);
        aL = fmaf(carry, p[c*5 + 3], aL);
        carry *= p[c*5 + 4];
    }
    const float bg = 1.0f - aL;
    out[3*r + 0] = aR + bg;
    out[3*r + 1] = aG + bg;
    out[3*r + 2] = aB + bg;
}

// ---------------------------------------------------------------------------
// Fallback: direct channel-major render if ws too small.
// ---------------------------------------------------------------------------
#define TRI8(p) (w000*(p)[o000] + w001*(p)[o001] + w010*(p)[o010] + w011*(p)[o011] \
               + w100*(p)[o100] + w101*(p)[o101] + w110*(p)[o110] + w111*(p)[o111])

__global__ __launch_bounds__(256)
void plenoxel_render_direct(const float* __restrict__ rays_o,
                            const float* __restrict__ rays_d,
                            const float* __restrict__ grid,
                            float* __restrict__ out)
{
    const int lane = threadIdx.x & 63;
    const int ray  = blockIdx.x * 4 + (threadIdx.x >> 6);

    const float ox = rays_o[3*ray+0], oy = rays_o[3*ray+1], oz = rays_o[3*ray+2];
    const float dx = rays_d[3*ray+0], dy = rays_d[3*ray+1], dz = rays_d[3*ray+2];

    const float sx = fminf(( kRadius - ox)/dx, (-kRadius - ox)/dx);
    const float sy = fminf(( kRadius - oy)/dy, (-kRadius - oy)/dy);
    const float sz = fminf(( kRadius - oz)/dz, (-kRadius - oz)/dz);
    const float start = fmaxf(sx, fmaxf(sy, sz));
    const float dnorm = sqrtf(dx*dx + dy*dy + dz*dz);

    float shm[9];
    shm[0] =  0.28209479177387814f;
    shm[1] = -0.4886025119029199f * dy;
    shm[2] =  0.4886025119029199f * dz;
    shm[3] = -0.4886025119029199f * dx;
    shm[4] =  1.0925484305920792f * dx * dy;
    shm[5] = -1.0925484305920792f * dy * dz;
    shm[6] =  0.31539156525252005f * (2.0f*dz*dz - dx*dx - dy*dy);
    shm[7] = -1.0925484305920792f * dx * dz;
    shm[8] =  0.5462742152960396f * (dx*dx - dy*dy);

    float carry = 1.0f;
    float accR = 0.f, accG = 0.f, accB = 0.f, accL = 0.f;

    for (int chunk = 0; chunk < kChunks7; ++chunk) {
        const int k = chunk * 64 + lane;
        float alpha = 0.0f, a = 1.0f;
        float rp0 = 0.f, rp1 = 0.f, rp2 = 0.f;
        bool inb = false;

        if (k < kNI) {
            const float t = start + (float)k * kStep;
            const float dist = kStep * dnorm;
            const float px = ox + t*dx, py = oy + t*dy, pz = oz + t*dz;
            inb = (px > -kRadius) && (px < kRadius) &&
                  (py > -kRadius) && (py < kRadius) &&
                  (pz > -kRadius) && (pz < kRadius);
            float sigma = 0.0f;
            if (inb) {
                const float cx = fminf(fmaxf((px*(1.0f/kRadius) + 1.0f)*0.5f*127.0f, 0.0f), 127.0f);
                const float cy = fminf(fmaxf((py*(1.0f/kRadius) + 1.0f)*0.5f*127.0f, 0.0f), 127.0f);
                const float cz = fminf(fmaxf((pz*(1.0f/kRadius) + 1.0f)*0.5f*127.0f, 0.0f), 127.0f);
                const float fx0 = floorf(cx), fy0 = floorf(cy), fz0 = floorf(cz);
                const float fx = cx - fx0, fy = cy - fy0, fz = cz - fz0;
                const int ix0 = (int)fx0, iy0 = (int)fy0, iz0 = (int)fz0;
                const int ix1 = min(ix0 + 1, 127);
                const int iy1 = min(iy0 + 1, 127);
                const int iz1 = min(iz0 + 1, 127);
                const float gx0 = 1.0f - fx, gy0 = 1.0f - fy, gz0 = 1.0f - fz;
                const float w000 = gz0*gy0*gx0, w001 = gz0*gy0*fx;
                const float w010 = gz0*fy *gx0, w011 = gz0*fy *fx;
                const float w100 = fz *gy0*gx0, w101 = fz *gy0*fx;
                const float w110 = fz *fy *gx0, w111 = fz *fy *fx;
                const int o000 = iz0*(kRes*kRes) + iy0*kRes + ix0;
                const int o001 = iz0*(kRes*kRes) + iy0*kRes + ix1;
                const int o010 = iz0*(kRes*kRes) + iy1*kRes + ix0;
                const int o011 = iz0*(kRes*kRes) + iy1*kRes + ix1;
                const int o100 = iz1*(kRes*kRes) + iy0*kRes + ix0;
                const int o101 = iz1*(kRes*kRes) + iy0*kRes + ix1;
                const int o110 = iz1*(kRes*kRes) + iy1*kRes + ix0;
                const int o111 = iz1*(kRes*kRes) + iy1*kRes + ix1;
                #pragma unroll
                for (int kk = 0; kk < 9; ++kk) {
                    rp0 = fmaf(shm[kk], TRI8(grid + (kk     ) * kChStride), rp0);
                    rp1 = fmaf(shm[kk], TRI8(grid + (kk +  9) * kChStride), rp1);
                    rp2 = fmaf(shm[kk], TRI8(grid + (kk + 18) * kChStride), rp2);
                }
                sigma = fmaxf(TRI8(grid + 27 * kChStride), 0.0f);
            }
            alpha = 1.0f - expf(-sigma * dist);
            a     = 1.0f - alpha + 1e-10f;
        }

        float prod = a;
        #pragma unroll
        for (int off = 1; off < 64; off <<= 1) {
            const float y = __shfl_up(prod, off, 64);
            if (lane >= off) prod *= y;
        }
        float excl = __shfl_up(prod, 1, 64);
        if (lane == 0) excl = 1.0f;
        const float trans = carry * excl;
        const float w = alpha * trans;
        if (inb) {
            accR = fmaf(w, 1.0f / (1.0f + expf(-rp0)), accR);
            accG = fmaf(w, 1.0f / (1.0f + expf(-rp1)), accG);
            accB = fmaf(w, 1.0f / (1.0f + expf(-rp2)), accB);
        }
        accL += w;
        carry *= __shfl(prod, 63, 64);
    }

    #pragma unroll
    for (int off = 32; off > 0; off >>= 1) {
        accR += __shfl_down(accR, off, 64);
        accG += __shfl_down(accG, off, 64);
        accB += __shfl_down(accB, off, 64);
        accL += __shfl_down(accL, off, 64);
    }

    if (lane == 0) {
        const float bg = 1.0f - accL;
        out[3*ray + 0] = accR + bg;
        out[3*ray + 1] = accG + bg;
        out[3*ray + 2] = accB + bg;
    }
}

extern "C" void kernel_launch(void* const* d_in, const int* in_sizes, int n_in,
                              void* d_out, int out_size, void* d_ws, size_t ws_size,
                              hipStream_t stream) {
    const float* rays_o = (const float*)d_in[0];
    const float* rays_d = (const float*)d_in[1];
    const float* data   = (const float*)d_in[2];   // (1,28,128,128,128)
    float* out = (float*)d_out;

    const size_t partBytes = (size_t)kNRays * kChunks * 5 * sizeof(float);
    const size_t need = kVoxBytes + partBytes;     // ~64.2 MB

    if (ws_size >= need) {
        unsigned char* vox = (unsigned char*)d_ws;
        float* partials = (float*)((char*)d_ws + kVoxBytes);

        hipLaunchKernelGGL(convert_grid,
                           dim3(kChStride / 1024), dim3(256), 0, stream,
                           data, vox);
        hipLaunchKernelGGL(render_chunks,
                           dim3(kNRays * kChunks / 4), dim3(256), 0, stream,
                           rays_o, rays_d, vox, partials);
        hipLaunchKernelGGL(combine_chunks,
                           dim3(kNRays / 256), dim3(256), 0, stream,
                           partials, out);
    } else {
        hipLaunchKernelGGL(plenoxel_render_direct,
                           dim3(kNRays / 4), dim3(256), 0, stream,
                           rays_o, rays_d, data, out);
    }
}

// Round 11
// 357.941 us; speedup vs baseline: 1.3446x; 1.1306x over previous
//
#include <hip/hip_runtime.h>
#include <math.h>

// Plenoxels renderer, round 11 = Morton render (R9/R10) + linear-read /
// Morton-scattered-write convert (no LDS).
//  - Reads stall, writes don't: convert reads exactly like round 7's proven
//    ~48us kernel (thread=linear voxel, per-channel wave-load = 256B
//    contiguous); the 32B record store goes to the Morton slot (even/odd x
//    pairs share a 64B line -> full-line scattered writes, 64MB total).
//  - 32B records: 27 SH fp8(e4m3) + sigma fp16 + pad; vox = 64MiB Morton.
//  - render: 4 samples/lane, 256-sample chunks, 2 chunks/ray, 8192 waves,
//    whole-wave early exit, folded sigmoid state.

typedef float f2v __attribute__((ext_vector_type(2)));

namespace {
constexpr float kRadius   = 1.3f;
constexpr int   kRes      = 128;
constexpr float kStep     = 2.0f * 1.3f / 128.0f / 2.0f;   // 0.01015625
constexpr int   kNI       = 443;                           // N_INTRS - 1
constexpr int   kNRays    = 4096;
constexpr int   kChStride = kRes * kRes * kRes;            // 2097152 voxels
constexpr int   kCh       = 28;
constexpr int   kRecBytes = 32;                            // 27 fp8 + f16 sigma + pad
constexpr size_t kVoxBytes = (size_t)kChStride * kRecBytes; // 64 MiB
constexpr int   kChunks   = 2;                             // 256-sample chunks
constexpr int   kChunks7  = 7;                             // fallback: 64-sample
}

// Morton helper: spread 7 bits into every 3rd position.
__device__ __forceinline__ unsigned part1by2(unsigned v)
{
    v &= 0x7Fu;
    v = (v | (v << 16)) & 0x030000FFu;
    v = (v | (v <<  8)) & 0x0300F00Fu;
    v = (v | (v <<  4)) & 0x030C30C3u;
    v = (v | (v <<  2)) & 0x09249249u;
    return v;
}

// ---------------------------------------------------------------------------
// Convert: thread = linear voxel (reads fully coalesced per channel, as in
// round 7); record written to its Morton slot (scattered full-line stores).
// ---------------------------------------------------------------------------
__global__ __launch_bounds__(256)
void convert_grid(const float* __restrict__ grid, unsigned char* __restrict__ vox)
{
    const unsigned lin = blockIdx.x * 256 + threadIdx.x;   // 8192 blocks
    const unsigned x = lin & 127u;
    const unsigned y = (lin >> 7) & 127u;
    const unsigned z = lin >> 14;
    const unsigned m = part1by2(x) | (part1by2(y) << 1) | (part1by2(z) << 2);

    float c[kCh];
    #pragma unroll
    for (int ch = 0; ch < kCh; ++ch)
        c[ch] = __builtin_nontemporal_load(grid + (size_t)ch * kChStride + lin);

    unsigned w[8];
    #pragma unroll
    for (int i = 0; i < 6; ++i) {
        int lo = __builtin_amdgcn_cvt_pk_fp8_f32(c[4*i],   c[4*i+1], 0,  false);
        w[i]   = (unsigned)__builtin_amdgcn_cvt_pk_fp8_f32(c[4*i+2], c[4*i+3], lo, true);
    }
    {   // word 6: ch24,25,26 + pad byte
        int lo = __builtin_amdgcn_cvt_pk_fp8_f32(c[24], c[25], 0,  false);
        w[6]   = (unsigned)__builtin_amdgcn_cvt_pk_fp8_f32(c[26], 0.0f, lo, true);
    }
    {   // word 7: fp16 sigma in low half
        union { unsigned short u; _Float16 h; } cv;
        cv.h = (_Float16)c[27];
        w[7] = (unsigned)cv.u;
    }

    uint4* dst = (uint4*)(vox + (size_t)m * kRecBytes);
    dst[0] = make_uint4(w[0], w[1], w[2], w[3]);
    dst[1] = make_uint4(w[4], w[5], w[6], w[7]);
}

// ---------------------------------------------------------------------------
// Per-sample eval with folded shading (Morton-indexed records).
// ---------------------------------------------------------------------------
struct SampleC { float a, cR, cG, cB; };

__device__ __forceinline__ SampleC eval_sample(
    int k, float start, float ox, float oy, float oz,
    float dx, float dy, float dz, float dist,
    const float* __restrict__ shm, const unsigned char* __restrict__ vox)
{
    SampleC s;
    s.a = 1.f; s.cR = s.cG = s.cB = 0.f;
    if (k >= kNI) return s;

    const float t  = start + (float)k * kStep;
    const float px = ox + t*dx;
    const float py = oy + t*dy;
    const float pz = oz + t*dz;
    const bool inb = (px > -kRadius) && (px < kRadius) &&
                     (py > -kRadius) && (py < kRadius) &&
                     (pz > -kRadius) && (pz < kRadius);

    float alpha = 0.0f;
    if (inb) {
        const float cx = fminf(fmaxf((px*(1.0f/kRadius) + 1.0f)*0.5f*127.0f, 0.0f), 127.0f);
        const float cy = fminf(fmaxf((py*(1.0f/kRadius) + 1.0f)*0.5f*127.0f, 0.0f), 127.0f);
        const float cz = fminf(fmaxf((pz*(1.0f/kRadius) + 1.0f)*0.5f*127.0f, 0.0f), 127.0f);
        const float fx0 = floorf(cx), fy0 = floorf(cy), fz0 = floorf(cz);
        const float fx = cx - fx0, fy = cy - fy0, fz = cz - fz0;
        const int ix0 = (int)fx0, iy0 = (int)fy0, iz0 = (int)fz0;
        const int ix1 = min(ix0 + 1, 127);
        const int iy1 = min(iy0 + 1, 127);
        const int iz1 = min(iz0 + 1, 127);

        const float gx0 = 1.0f - fx, gy0 = 1.0f - fy, gz0 = 1.0f - fz;

        const unsigned X0 = part1by2((unsigned)ix0);
        const unsigned X1 = part1by2((unsigned)ix1);
        const unsigned Y0 = part1by2((unsigned)iy0) << 1;
        const unsigned Y1 = part1by2((unsigned)iy1) << 1;
        const unsigned Z0 = part1by2((unsigned)iz0) << 2;
        const unsigned Z1 = part1by2((unsigned)iz1) << 2;

        const unsigned offs[8] = {
            Z0 | Y0 | X0,  Z0 | Y0 | X1,  Z0 | Y1 | X0,  Z0 | Y1 | X1,
            Z1 | Y0 | X0,  Z1 | Y0 | X1,  Z1 | Y1 | X0,  Z1 | Y1 | X1 };
        const float cw[8] = {
            gz0*gy0*gx0, gz0*gy0*fx, gz0*fy*gx0, gz0*fy*fx,
            fz *gy0*gx0, fz *gy0*fx, fz *fy*gx0, fz *fy*fx };

        float rp0 = 0.f, rp1 = 0.f, rp2 = 0.f, sig = 0.f;
        #pragma unroll
        for (int cn = 0; cn < 8; ++cn) {
            const uint4* vp = (const uint4*)(vox + (size_t)offs[cn] * kRecBytes);
            const uint4 u0 = vp[0], u1 = vp[1];

            float f[28];
            const unsigned wd[7] = { u0.x, u0.y, u0.z, u0.w, u1.x, u1.y, u1.z };
            #pragma unroll
            for (int i = 0; i < 7; ++i) {
                const f2v lo = __builtin_amdgcn_cvt_pk_f32_fp8((int)wd[i], false);
                const f2v hi = __builtin_amdgcn_cvt_pk_f32_fp8((int)wd[i], true);
                f[4*i+0] = lo.x; f[4*i+1] = lo.y; f[4*i+2] = hi.x; f[4*i+3] = hi.y;
            }
            union { unsigned short u; _Float16 h; } cv;
            cv.u = (unsigned short)(u1.w & 0xffffu);
            const float sv = (float)cv.h;

            float r = 0.f, g = 0.f, b = 0.f;
            #pragma unroll
            for (int j = 0; j < 9; ++j) {
                r = fmaf(shm[j], f[j],      r);
                g = fmaf(shm[j], f[9 + j],  g);
                b = fmaf(shm[j], f[18 + j], b);
            }
            const float wc = cw[cn];
            rp0 = fmaf(wc, r, rp0);
            rp1 = fmaf(wc, g, rp1);
            rp2 = fmaf(wc, b, rp2);
            sig = fmaf(wc, sv, sig);
        }
        sig = fmaxf(sig, 0.0f);
        alpha = 1.0f - expf(-sig * dist);
        s.cR = alpha * (1.0f / (1.0f + expf(-rp0)));
        s.cG = alpha * (1.0f / (1.0f + expf(-rp1)));
        s.cB = alpha * (1.0f / (1.0f + expf(-rp2)));
    }
    s.a = 1.0f - alpha + 1e-10f;
    return s;
}

__device__ __forceinline__ float wave_scan_prod(float a, int lane, float& total)
{
    float prod = a;
    #pragma unroll
    for (int off = 1; off < 64; off <<= 1) {
        const float y = __shfl_up(prod, off, 64);
        if (lane >= off) prod *= y;
    }
    float excl = __shfl_up(prod, 1, 64);
    if (lane == 0) excl = 1.0f;
    total = __shfl(prod, 63, 64);
    return excl;
}

// ---------------------------------------------------------------------------
// Render one 256-sample chunk of one ray per wave.
// ---------------------------------------------------------------------------
__global__ __launch_bounds__(256, 3)
void render_chunks(const float* __restrict__ rays_o,
                   const float* __restrict__ rays_d,
                   const unsigned char* __restrict__ vox,
                   float* __restrict__ partials)           // (4096,2,5)
{
    const int lane  = threadIdx.x & 63;
    const int W     = blockIdx.x * 4 + (threadIdx.x >> 6); // 8192 waves
    const int ray   = W >> 1;
    const int chunk = W & 1;

    const float ox = rays_o[3*ray+0], oy = rays_o[3*ray+1], oz = rays_o[3*ray+2];
    const float dx = rays_d[3*ray+0], dy = rays_d[3*ray+1], dz = rays_d[3*ray+2];

    const float ppx = ( kRadius - ox)/dx, pnx = (-kRadius - ox)/dx;
    const float ppy = ( kRadius - oy)/dy, pny = (-kRadius - oy)/dy;
    const float ppz = ( kRadius - oz)/dz, pnz = (-kRadius - oz)/dz;
    const float start  = fmaxf(fminf(ppx, pnx), fmaxf(fminf(ppy, pny), fminf(ppz, pnz)));
    const float t_exit = fminf(fmaxf(ppx, pnx), fminf(fmaxf(ppy, pny), fmaxf(ppz, pnz)));

    const int base = chunk * 256;

    if (start + (float)base * kStep > t_exit + kStep) {
        if (lane == 0) {
            float* p = partials + (size_t)(ray * kChunks + chunk) * 5;
            p[0] = 0.f; p[1] = 0.f; p[2] = 0.f; p[3] = 0.f; p[4] = 1.f;
        }
        return;
    }

    const float dnorm = sqrtf(dx*dx + dy*dy + dz*dz);
    const float dist  = kStep * dnorm;

    float shm[9];
    shm[0] =  0.28209479177387814f;
    shm[1] = -0.4886025119029199f * dy;
    shm[2] =  0.4886025119029199f * dz;
    shm[3] = -0.4886025119029199f * dx;
    shm[4] =  1.0925484305920792f * dx * dy;
    shm[5] = -1.0925484305920792f * dy * dz;
    shm[6] =  0.31539156525252005f * (2.0f*dz*dz - dx*dx - dy*dy);
    shm[7] = -1.0925484305920792f * dx * dz;
    shm[8] =  0.5462742152960396f * (dx*dx - dy*dy);

    const SampleC A = eval_sample(base       + lane, start, ox, oy, oz, dx, dy, dz, dist, shm, vox);
    const SampleC B = eval_sample(base +  64 + lane, start, ox, oy, oz, dx, dy, dz, dist, shm, vox);
    const SampleC C = eval_sample(base + 128 + lane, start, ox, oy, oz, dx, dy, dz, dist, shm, vox);
    const SampleC D = eval_sample(base + 192 + lane, start, ox, oy, oz, dx, dy, dz, dist, shm, vox);

    float P0, P1, P2, P3;
    const float eA = wave_scan_prod(A.a, lane, P0);
    const float eB = wave_scan_prod(B.a, lane, P1);
    const float eC = wave_scan_prod(C.a, lane, P2);
    const float eD = wave_scan_prod(D.a, lane, P3);

    const float pA = eA;
    const float pB = P0 * eB;
    const float pC = P0 * P1 * eC;
    const float pD = P0 * P1 * P2 * eD;

    const float one = 1.0f + 1e-10f;
    float rL = pA * (one - A.a) + pB * (one - B.a)
             + pC * (one - C.a) + pD * (one - D.a);

    float rR = pA * A.cR;  rR = fmaf(pB, B.cR, rR);
    rR = fmaf(pC, C.cR, rR);  rR = fmaf(pD, D.cR, rR);
    float rG = pA * A.cG;  rG = fmaf(pB, B.cG, rG);
    rG = fmaf(pC, C.cG, rG);  rG = fmaf(pD, D.cG, rG);
    float rB = pA * A.cB;  rB = fmaf(pB, B.cB, rB);
    rB = fmaf(pC, C.cB, rB);  rB = fmaf(pD, D.cB, rB);

    const float P = P0 * P1 * P2 * P3;

    #pragma unroll
    for (int off = 32; off > 0; off >>= 1) {
        rR += __shfl_down(rR, off, 64);
        rG += __shfl_down(rG, off, 64);
        rB += __shfl_down(rB, off, 64);
        rL += __shfl_down(rL, off, 64);
    }

    if (lane == 0) {
        float* p = partials + (size_t)(ray * kChunks + chunk) * 5;
        p[0] = rR; p[1] = rG; p[2] = rB; p[3] = rL; p[4] = P;
    }
}

// ---------------------------------------------------------------------------
// Stitch chunk partials.
// ---------------------------------------------------------------------------
__global__ __launch_bounds__(256)
void combine_chunks(const float* __restrict__ partials, float* __restrict__ out)
{
    const int r = blockIdx.x * 256 + threadIdx.x;          // 16 blocks
    const float* p = partials + (size_t)r * (kChunks * 5);

    float carry = 1.0f, aR = 0.f, aG = 0.f, aB = 0.f, aL = 0.f;
    #pragma unroll
    for (int c = 0; c < kChunks; ++c) {
        aR = fmaf(carry, p[c*5 + 0], aR);
        aG = fmaf(carry, p[c*5 + 1], aG);
        aB = fmaf(carry, p[c*5 + 2], aB);
        aL = fmaf(carry, p[c*5 + 3], aL);
        carry *= p[c*5 + 4];
    }
    const float bg = 1.0f - aL;
    out[3*r + 0] = aR + bg;
    out[3*r + 1] = aG + bg;
    out[3*r + 2] = aB + bg;
}

// ---------------------------------------------------------------------------
// Fallback: direct channel-major render if ws too small.
// ---------------------------------------------------------------------------
#define TRI8(p) (w000*(p)[o000] + w001*(p)[o001] + w010*(p)[o010] + w011*(p)[o011] \
               + w100*(p)[o100] + w101*(p)[o101] + w110*(p)[o110] + w111*(p)[o111])

__global__ __launch_bounds__(256)
void plenoxel_render_direct(const float* __restrict__ rays_o,
                            const float* __restrict__ rays_d,
                            const float* __restrict__ grid,
                            float* __restrict__ out)
{
    const int lane = threadIdx.x & 63;
    const int ray  = blockIdx.x * 4 + (threadIdx.x >> 6);

    const float ox = rays_o[3*ray+0], oy = rays_o[3*ray+1], oz = rays_o[3*ray+2];
    const float dx = rays_d[3*ray+0], dy = rays_d[3*ray+1], dz = rays_d[3*ray+2];

    const float sx = fminf(( kRadius - ox)/dx, (-kRadius - ox)/dx);
    const float sy = fminf(( kRadius - oy)/dy, (-kRadius - oy)/dy);
    const float sz = fminf(( kRadius - oz)/dz, (-kRadius - oz)/dz);
    const float start = fmaxf(sx, fmaxf(sy, sz));
    const float dnorm = sqrtf(dx*dx + dy*dy + dz*dz);

    float shm[9];
    shm[0] =  0.28209479177387814f;
    shm[1] = -0.4886025119029199f * dy;
    shm[2] =  0.4886025119029199f * dz;
    shm[3] = -0.4886025119029199f * dx;
    shm[4] =  1.0925484305920792f * dx * dy;
    shm[5] = -1.0925484305920792f * dy * dz;
    shm[6] =  0.31539156525252005f * (2.0f*dz*dz - dx*dx - dy*dy);
    shm[7] = -1.0925484305920792f * dx * dz;
    shm[8] =  0.5462742152960396f * (dx*dx - dy*dy);

    float carry = 1.0f;
    float accR = 0.f, accG = 0.f, accB = 0.f, accL = 0.f;

    for (int chunk = 0; chunk < kChunks7; ++chunk) {
        const int k = chunk * 64 + lane;
        float alpha = 0.0f, a = 1.0f;
        float rp0 = 0.f, rp1 = 0.f, rp2 = 0.f;
        bool inb = false;

        if (k < kNI) {
            const float t = start + (float)k * kStep;
            const float dist = kStep * dnorm;
            const float px = ox + t*dx, py = oy + t*dy, pz = oz + t*dz;
            inb = (px > -kRadius) && (px < kRadius) &&
                  (py > -kRadius) && (py < kRadius) &&
                  (pz > -kRadius) && (pz < kRadius);
            float sigma = 0.0f;
            if (inb) {
                const float cx = fminf(fmaxf((px*(1.0f/kRadius) + 1.0f)*0.5f*127.0f, 0.0f), 127.0f);
                const float cy = fminf(fmaxf((py*(1.0f/kRadius) + 1.0f)*0.5f*127.0f, 0.0f), 127.0f);
                const float cz = fminf(fmaxf((pz*(1.0f/kRadius) + 1.0f)*0.5f*127.0f, 0.0f), 127.0f);
                const float fx0 = floorf(cx), fy0 = floorf(cy), fz0 = floorf(cz);
                const float fx = cx - fx0, fy = cy - fy0, fz = cz - fz0;
                const int ix0 = (int)fx0, iy0 = (int)fy0, iz0 = (int)fz0;
                const int ix1 = min(ix0 + 1, 127);
                const int iy1 = min(iy0 + 1, 127);
                const int iz1 = min(iz0 + 1, 127);
                const float gx0 = 1.0f - fx, gy0 = 1.0f - fy, gz0 = 1.0f - fz;
                const float w000 = gz0*gy0*gx0, w001 = gz0*gy0*fx;
                const float w010 = gz0*fy *gx0, w011 = gz0*fy *fx;
                const float w100 = fz *gy0*gx0, w101 = fz *gy0*fx;
                const float w110 = fz *fy *gx0, w111 = fz *fy *fx;
                const int o000 = iz0*(kRes*kRes) + iy0*kRes + ix0;
                const int o001 = iz0*(kRes*kRes) + iy0*kRes + ix1;
                const int o010 = iz0*(kRes*kRes) + iy1*kRes + ix0;
                const int o011 = iz0*(kRes*kRes) + iy1*kRes + ix1;
                const int o100 = iz1*(kRes*kRes) + iy0*kRes + ix0;
                const int o101 = iz1*(kRes*kRes) + iy0*kRes + ix1;
                const int o110 = iz1*(kRes*kRes) + iy1*kRes + ix0;
                const int o111 = iz1*(kRes*kRes) + iy1*kRes + ix1;
                #pragma unroll
                for (int kk = 0; kk < 9; ++kk) {
                    rp0 = fmaf(shm[kk], TRI8(grid + (kk     ) * kChStride), rp0);
                    rp1 = fmaf(shm[kk], TRI8(grid + (kk +  9) * kChStride), rp1);
                    rp2 = fmaf(shm[kk], TRI8(grid + (kk + 18) * kChStride), rp2);
                }
                sigma = fmaxf(TRI8(grid + 27 * kChStride), 0.0f);
            }
            alpha = 1.0f - expf(-sigma * dist);
            a     = 1.0f - alpha + 1e-10f;
        }

        float prod = a;
        #pragma unroll
        for (int off = 1; off < 64; off <<= 1) {
            const float y = __shfl_up(prod, off, 64);
            if (lane >= off) prod *= y;
        }
        float excl = __shfl_up(prod, 1, 64);
        if (lane == 0) excl = 1.0f;
        const float trans = carry * excl;
        const float w = alpha * trans;
        if (inb) {
            accR = fmaf(w, 1.0f / (1.0f + expf(-rp0)), accR);
            accG = fmaf(w, 1.0f / (1.0f + expf(-rp1)), accG);
            accB = fmaf(w, 1.0f / (1.0f + expf(-rp2)), accB);
        }
        accL += w;
        carry *= __shfl(prod, 63, 64);
    }

    #pragma unroll
    for (int off = 32; off > 0; off >>= 1) {
        accR += __shfl_down(accR, off, 64);
        accG += __shfl_down(accG, off, 64);
        accB += __shfl_down(accB, off, 64);
        accL += __shfl_down(accL, off, 64);
    }

    if (lane == 0) {
        const float bg = 1.0f - accL;
        out[3*ray + 0] = accR + bg;
        out[3*ray + 1] = accG + bg;
        out[3*ray + 2] = accB + bg;
    }
}

extern "C" void kernel_launch(void* const* d_in, const int* in_sizes, int n_in,
                              void* d_out, int out_size, void* d_ws, size_t ws_size,
                              hipStream_t stream) {
    const float* rays_o = (const float*)d_in[0];
    const float* rays_d = (const float*)d_in[1];
    const float* data   = (const float*)d_in[2];   // (1,28,128,128,128)
    float* out = (float*)d_out;

    const size_t partBytes = (size_t)kNRays * kChunks * 5 * sizeof(float);
    const size_t need = kVoxBytes + partBytes;     // ~64.2 MB

    if (ws_size >= need) {
        unsigned char* vox = (unsigned char*)d_ws;
        float* partials = (float*)((char*)d_ws + kVoxBytes);

        hipLaunchKernelGGL(convert_grid,
                           dim3(kChStride / 256), dim3(256), 0, stream,
                           data, vox);
        hipLaunchKernelGGL(render_chunks,
                           dim3(kNRays * kChunks / 4), dim3(256), 0, stream,
                           rays_o, rays_d, vox, partials);
        hipLaunchKernelGGL(combine_chunks,
                           dim3(kNRays / 256), dim3(256), 0, stream,
                           partials, out);
    } else {
        hipLaunchKernelGGL(plenoxel_render_direct,
                           dim3(kNRays / 4), dim3(256), 0, stream,
                           rays_o, rays_d, data, out);
    }
}